// Round 7
// baseline (253.429 us; speedup 1.0000x reference)
//
#include <hip/hip_runtime.h>
#include <hip/hip_bf16.h>

// NonLocalBlock1D, algebraically collapsed + split-bf16 MFMA.
//   S[b]  = g_pool[b] @ phi_pool[b]^T      (128x128)
//   M[b]  = w_w @ S[b] / N                 (256x128)
//   W2[b] = M[b] @ theta_w                 (256x256), b2[b] = M[b]@theta_b + w_b
//   wy[b] = W2[b] @ x[b] + b2[b]  -> BN stats pass + fused BN-apply pass
// Round-6/7: MFMA-native TILED global layouts [tile][kc(32)][row(128)][16B] for
// x and all weight operands. A-stage = linear 64KB global_load_lds copy
// (coalesced), LDS [kc][row] = conflict-free ds_read; B-frags direct from
// global (4x256B coalesced segments). 3-phase K-loop, no per-step barriers.

constexpr int B = 4, C = 256, CI = 128, T = 8192, NN = 4096;

using s16x8 = __attribute__((ext_vector_type(8))) short;
using f32x4 = __attribute__((ext_vector_type(4))) float;

__device__ __forceinline__ unsigned short f2bf(float f) {
    unsigned int x = __float_as_uint(f);
    unsigned int r = (x + 0x7fffu + ((x >> 16) & 1u)) >> 16;   // RNE
    return (unsigned short)r;
}
__device__ __forceinline__ float bf2f(unsigned short u) {
    return __uint_as_float((unsigned int)u << 16);
}

#define MFMA(a, b, c) __builtin_amdgcn_mfma_f32_16x16x32_bf16((a), (b), (c), 0, 0, 0)

__device__ __forceinline__ void glds16(const unsigned short* g, void* l) {
    __builtin_amdgcn_global_load_lds(
        (const __attribute__((address_space(1))) unsigned int*)(g),
        (__attribute__((address_space(3))) unsigned int*)(l), 16, 0, 0);
}

// Tiled layout: tile = 128 rows x 256 k of bf16 = 65536 B = 32768 u16.
//   u16 offset(tile, kc, row, j) = tile*32768 + kc*1024 + row*8 + j
// xth/xtl: tile = b*(T/128) + t/128, row = t%128, kc = c/8.
// wsh/wsl: tile = isG (phi=0, g=1), row = o%128.
// w2h/w2l: tile = b*2 + o/128.

// ---- ws layout (bytes) ----
constexpr size_t SZ_XT = (size_t)B * T * C * 2;        // 16MB each
constexpr size_t O_XTH = 0;
constexpr size_t O_XTL = O_XTH + SZ_XT;
constexpr size_t O_WSH = O_XTL + SZ_XT;                // stacked [phi;g] weights bf16
constexpr size_t O_WSL = O_WSH + (size_t)C * C * 2;
constexpr size_t SZ_P  = (size_t)B * CI * NN * 2;      // 4MB each pool array
constexpr size_t O_PH  = O_WSL + (size_t)C * C * 2;
constexpr size_t O_PL  = O_PH + SZ_P;
constexpr size_t O_GH  = O_PL + SZ_P;
constexpr size_t O_GL  = O_GH + SZ_P;
constexpr size_t O_S   = O_GL + SZ_P;                  // fp32 B*CI*CI
constexpr size_t O_M   = O_S  + (size_t)B * CI * CI * 4;
constexpr size_t O_W2H = O_M  + (size_t)B * C * CI * 4;
constexpr size_t O_W2L = O_W2H + (size_t)B * C * C * 2;
constexpr size_t O_B2  = O_W2L + (size_t)B * C * C * 2;
constexpr size_t O_GS  = O_B2 + (size_t)B * C * 4;
constexpr size_t O_GQ  = O_GS + (size_t)C * 4;
constexpr size_t O_A   = O_GQ + (size_t)C * 4;
constexpr size_t O_SH  = O_A  + (size_t)C * 4;

// K0: x (B,C,T) fp32 -> tiled hi/lo bf16
__global__ __launch_bounds__(256) void k0_split(
    const float* __restrict__ x, unsigned short* __restrict__ xth,
    unsigned short* __restrict__ xtl)
{
    __shared__ float xs[64][65];   // [t][c], padded
    int t0 = blockIdx.x * 64, c0 = blockIdx.y * 64, b = blockIdx.z;
    int tid = threadIdx.x;
    const float* xb = x + (size_t)b * C * T;
    #pragma unroll
    for (int p = 0; p < 4; ++p) {
        int idx = tid + p * 256;
        int cr = idx >> 4;           // c-local
        int tg = (idx & 15) * 4;     // t-local
        float4 v = *reinterpret_cast<const float4*>(xb + (size_t)(c0 + cr) * T + t0 + tg);
        xs[tg + 0][cr] = v.x; xs[tg + 1][cr] = v.y;
        xs[tg + 2][cr] = v.z; xs[tg + 3][cr] = v.w;
    }
    __syncthreads();
    size_t tileBase = ((size_t)b * (T / 128) + (t0 >> 7)) * 32768;
    int trBase = t0 & 127;           // 0 or 64
    #pragma unroll
    for (int p = 0; p < 2; ++p) {
        int idx = tid + p * 256;
        int kcL = idx >> 6;          // 0..7 (chunk within this 64-c block)
        int tl  = idx & 63;
        s16x8 hs, ls;
        #pragma unroll
        for (int j = 0; j < 8; ++j) {
            float v = xs[tl][kcL * 8 + j];
            unsigned short h = f2bf(v);
            unsigned short l = f2bf(v - bf2f(h));
            hs[j] = (short)h; ls[j] = (short)l;
        }
        size_t dst = tileBase + (size_t)((c0 >> 3) + kcL) * 1024 + (trBase + tl) * 8;
        *reinterpret_cast<s16x8*>(xth + dst) = hs;
        *reinterpret_cast<s16x8*>(xtl + dst) = ls;
    }
}

// K0w: stack [phi_w; g_w] -> tiled hi/lo bf16 (tile0=phi, tile1=g)
__global__ __launch_bounds__(256) void k0w(
    const float* __restrict__ phi_w, const float* __restrict__ g_w,
    unsigned short* __restrict__ wsh, unsigned short* __restrict__ wsl)
{
    int idx = blockIdx.x * 256 + threadIdx.x;   // 8192 threads
    int c8 = idx & 31, row = idx >> 5;          // row 0..255
    const float* src = (row < CI) ? &phi_w[(size_t)row * C + c8 * 8]
                                  : &g_w[(size_t)(row - CI) * C + c8 * 8];
    s16x8 hs, ls;
    #pragma unroll
    for (int j = 0; j < 8; ++j) {
        float v = src[j];
        unsigned short h = f2bf(v);
        hs[j] = (short)h; ls[j] = (short)f2bf(v - bf2f(h));
    }
    size_t dst = (size_t)(row >> 7) * 32768 + (size_t)c8 * 1024 + (row & 127) * 8;
    *reinterpret_cast<s16x8*>(wsh + dst) = hs;
    *reinterpret_cast<s16x8*>(wsl + dst) = ls;
}

// ---- shared GEMM core ----
// Block: 128 t x 128 o, 4 waves (2 wt x 2 wo). A staged in LDS (64KB,
// [kc][row]); B direct from tiled global. 3 phases: (xh,Bh)x8, (xh,Bl)x8,
// then restage A=xl, (xl,Bh)x8.
#define STAGE_A(srcT) {                                                        \
    _Pragma("unroll")                                                          \
    for (int i_ = 0; i_ < 16; ++i_)                                            \
        glds16((srcT) + (size_t)(w * 8192 + i_ * 512 + lane * 8),              \
               arena + w * 16384 + i_ * 1024);                                 \
}

#define K8(BT) {                                                               \
    _Pragma("unroll")                                                          \
    for (int ks_ = 0; ks_ < 8; ++ks_) {                                        \
        s16x8 af[4], bfr[4];                                                   \
        _Pragma("unroll")                                                      \
        for (int ts_ = 0; ts_ < 4; ++ts_)                                      \
            af[ts_] = *(const s16x8*)(arena + (ks_ * 4 + lk) * 2048            \
                                      + (wt * 64 + ts_ * 16 + lr) * 16);       \
        _Pragma("unroll")                                                      \
        for (int os_ = 0; os_ < 4; ++os_)                                      \
            bfr[os_] = *(const s16x8*)((BT) + (size_t)(ks_ * 4 + lk) * 1024    \
                                       + (wo * 64 + os_ * 16 + lr) * 8);       \
        _Pragma("unroll")                                                      \
        for (int os_ = 0; os_ < 4; ++os_)                                      \
            _Pragma("unroll")                                                  \
            for (int ts_ = 0; ts_ < 4; ++ts_)                                  \
                acc[os_][ts_] = MFMA(af[ts_], bfr[os_], acc[os_][ts_]);        \
    }                                                                          \
}

#define GEMM_3PHASE(aT_h, aT_l, bT_h, bT_l) {                                  \
    STAGE_A(aT_h);                                                             \
    __syncthreads();                                                           \
    K8(bT_h);                                                                  \
    K8(bT_l);                                                                  \
    __syncthreads();                                                           \
    STAGE_A(aT_l);                                                             \
    __syncthreads();                                                           \
    K8(bT_h);                                                                  \
}

// K1: pooled [phi;g] conv. Grid (T/128, 2, B): y=0 -> phi, y=1 -> g.
__global__ __launch_bounds__(256) void k1_mfma(
    const unsigned short* __restrict__ xth, const unsigned short* __restrict__ xtl,
    const unsigned short* __restrict__ wsh, const unsigned short* __restrict__ wsl,
    const float* __restrict__ phi_b, const float* __restrict__ g_b,
    unsigned short* __restrict__ ph, unsigned short* __restrict__ pl,
    unsigned short* __restrict__ gh, unsigned short* __restrict__ gl)
{
    const int b = blockIdx.z, t0 = blockIdx.x * 128, isG = blockIdx.y;
    __shared__ __align__(16) char arena[65536];
    const int tid = threadIdx.x, lane = tid & 63, w = tid >> 6;
    const int lr = lane & 15, lk = lane >> 4;
    const int wt = w >> 1, wo = w & 1;

    const unsigned short* aTh = xth + ((size_t)b * (T / 128) + (t0 >> 7)) * 32768;
    const unsigned short* aTl = xtl + ((size_t)b * (T / 128) + (t0 >> 7)) * 32768;
    const unsigned short* bTh = wsh + (size_t)isG * 32768;
    const unsigned short* bTl = wsl + (size_t)isG * 32768;

    f32x4 acc[4][4];
    #pragma unroll
    for (int i = 0; i < 4; ++i)
        #pragma unroll
        for (int j = 0; j < 4; ++j) acc[i][j] = (f32x4){0.f, 0.f, 0.f, 0.f};

    GEMM_3PHASE(aTh, aTl, bTh, bTl)
    __syncthreads();   // arena free for pool overlay

    unsigned int (*pool_s)[65] = (unsigned int (*)[65])arena;
    const float* biasArr = isG ? g_b : phi_b;
    #pragma unroll
    for (int os = 0; os < 4; ++os) {
        int oL = wo * 64 + os * 16 + lr;
        float bias = biasArr[oL];
        #pragma unroll
        for (int ts = 0; ts < 4; ++ts) {
            f32x4 v = acc[os][ts];
            float m0 = fmaxf(v[0], v[1]) + bias;
            float m1 = fmaxf(v[2], v[3]) + bias;
            int nl = wt * 32 + ts * 8 + lk * 2;   // t = wt*64+ts*16+lk*4+r -> n=t/2
            unsigned short h0 = f2bf(m0), h1 = f2bf(m1);
            pool_s[oL][nl]     = (unsigned int)h0 | ((unsigned int)f2bf(m0 - bf2f(h0)) << 16);
            pool_s[oL][nl + 1] = (unsigned int)h1 | ((unsigned int)f2bf(m1 - bf2f(h1)) << 16);
        }
    }
    __syncthreads();
    int oL = tid >> 1, seg = tid & 1;
    size_t n0 = (size_t)(t0 >> 1) + seg * 32;
    unsigned short* dh = (isG ? gh : ph) + ((size_t)b * CI + oL) * NN + n0;
    unsigned short* dl = (isG ? gl : pl) + ((size_t)b * CI + oL) * NN + n0;
    #pragma unroll
    for (int g4 = 0; g4 < 4; ++g4) {
        s16x8 hs, ls;
        #pragma unroll
        for (int j = 0; j < 8; ++j) {
            unsigned int u = pool_s[oL][seg * 32 + g4 * 8 + j];
            hs[j] = (short)(u & 0xffffu);
            ls[j] = (short)(u >> 16);
        }
        *reinterpret_cast<s16x8*>(dh + g4 * 8) = hs;
        *reinterpret_cast<s16x8*>(dl + g4 * 8) = ls;
    }
}

// K45: wy = W2[b]@x + b2.  MODE 0: BN stats (atomics).  MODE 1: out = a*wy+sh+x.
template <int MODE>
__global__ __launch_bounds__(256) void k45_mfma(
    const unsigned short* __restrict__ xth, const unsigned short* __restrict__ xtl,
    const unsigned short* __restrict__ w2h, const unsigned short* __restrict__ w2l,
    const float* __restrict__ b2, const float* __restrict__ x,
    const float* __restrict__ abuf, const float* __restrict__ shbuf,
    float* __restrict__ gsum, float* __restrict__ gsq, float* __restrict__ out)
{
    const int b = blockIdx.z, t0 = blockIdx.x * 128, oHalf = blockIdx.y;
    const int o0 = oHalf * 128;
    __shared__ __align__(16) char arena[65536];
    const int tid = threadIdx.x, lane = tid & 63, w = tid >> 6;
    const int lr = lane & 15, lk = lane >> 4;
    const int wt = w >> 1, wo = w & 1;

    const unsigned short* aTh = xth + ((size_t)b * (T / 128) + (t0 >> 7)) * 32768;
    const unsigned short* aTl = xtl + ((size_t)b * (T / 128) + (t0 >> 7)) * 32768;
    const unsigned short* bTh = w2h + ((size_t)b * 2 + oHalf) * 32768;
    const unsigned short* bTl = w2l + ((size_t)b * 2 + oHalf) * 32768;

    f32x4 acc[4][4];
    #pragma unroll
    for (int i = 0; i < 4; ++i)
        #pragma unroll
        for (int j = 0; j < 4; ++j) acc[i][j] = (f32x4){0.f, 0.f, 0.f, 0.f};

    GEMM_3PHASE(aTh, aTl, bTh, bTl)

    #pragma unroll
    for (int os = 0; os < 4; ++os) {
        int o = o0 + wo * 64 + os * 16 + lr;
        float bv = b2[(size_t)b * C + o];
        if (MODE == 0) {
            float s = 0.f, q = 0.f;
            #pragma unroll
            for (int ts = 0; ts < 4; ++ts)
                #pragma unroll
                for (int r = 0; r < 4; ++r) {
                    float v = acc[os][ts][r] + bv;
                    s += v; q += v * v;
                }
            s += __shfl_xor(s, 16); s += __shfl_xor(s, 32);
            q += __shfl_xor(q, 16); q += __shfl_xor(q, 32);
            if (lk == 0) { atomicAdd(&gsum[o], s); atomicAdd(&gsq[o], q); }
        } else {
            float av = abuf[o], sv = shbuf[o];
            #pragma unroll
            for (int ts = 0; ts < 4; ++ts) {
                int t = t0 + wt * 64 + ts * 16 + lk * 4;
                size_t base = ((size_t)b * C + o) * T + t;
                float4 xv = *reinterpret_cast<const float4*>(x + base);
                float4 ov;
                ov.x = av * (acc[os][ts][0] + bv) + sv + xv.x;
                ov.y = av * (acc[os][ts][1] + bv) + sv + xv.y;
                ov.z = av * (acc[os][ts][2] + bv) + sv + xv.z;
                ov.w = av * (acc[os][ts][3] + bv) + sv + xv.w;
                *reinterpret_cast<float4*>(out + base) = ov;
            }
        }
    }
}

// K2: S[b,i,j] = sum_n g[i,n]*phi[j,n], split MFMA, atomic partials.
__global__ __launch_bounds__(256) void k2_mfma(
    const unsigned short* __restrict__ ph, const unsigned short* __restrict__ pl,
    const unsigned short* __restrict__ gh, const unsigned short* __restrict__ gl,
    float* __restrict__ S)
{
    int b = blockIdx.y, n0 = blockIdx.x * 128;
    int tid = threadIdx.x, lane = tid & 63, w = tid >> 6;
    int lr = lane & 15, lk = lane >> 4;

    f32x4 acc[2][8];   // [isub][jsub]
    #pragma unroll
    for (int i = 0; i < 2; ++i)
        #pragma unroll
        for (int j = 0; j < 8; ++j) acc[i][j] = (f32x4){0.f, 0.f, 0.f, 0.f};

    const unsigned short* ah_b = gh + ((size_t)b * CI + w * 32 + lr) * NN + n0 + lk * 8;
    const unsigned short* al_b = gl + ((size_t)b * CI + w * 32 + lr) * NN + n0 + lk * 8;
    const unsigned short* bh_b = ph + ((size_t)b * CI + lr) * NN + n0 + lk * 8;
    const unsigned short* bl_b = pl + ((size_t)b * CI + lr) * NN + n0 + lk * 8;

    for (int ks = 0; ks < 4; ++ks) {
        s16x8 Ah[2], Al[2], Bh[8], Bl[8];
        #pragma unroll
        for (int is = 0; is < 2; ++is) {
            Ah[is] = *reinterpret_cast<const s16x8*>(ah_b + (size_t)is * 16 * NN + ks * 32);
            Al[is] = *reinterpret_cast<const s16x8*>(al_b + (size_t)is * 16 * NN + ks * 32);
        }
        #pragma unroll
        for (int js = 0; js < 8; ++js) {
            Bh[js] = *reinterpret_cast<const s16x8*>(bh_b + (size_t)js * 16 * NN + ks * 32);
            Bl[js] = *reinterpret_cast<const s16x8*>(bl_b + (size_t)js * 16 * NN + ks * 32);
        }
        #pragma unroll
        for (int is = 0; is < 2; ++is)
            #pragma unroll
            for (int js = 0; js < 8; ++js) {
                acc[is][js] = MFMA(Ah[is], Bh[js], acc[is][js]);
                acc[is][js] = MFMA(Al[is], Bh[js], acc[is][js]);
                acc[is][js] = MFMA(Ah[is], Bl[js], acc[is][js]);
            }
    }
    #pragma unroll
    for (int is = 0; is < 2; ++is) {
        int i0 = w * 32 + is * 16 + lk * 4;
        #pragma unroll
        for (int js = 0; js < 8; ++js) {
            int j = js * 16 + lr;
            #pragma unroll
            for (int r = 0; r < 4; ++r)
                atomicAdd(&S[((size_t)b * CI + i0 + r) * CI + j], acc[is][js][r]);
        }
    }
}

// K3a: M[b] = w_w @ S[b] / N   (float4 over j)
__global__ __launch_bounds__(256) void k3a_M(
    const float* __restrict__ w_w, const float* __restrict__ S, float* __restrict__ M)
{
    int idx = blockIdx.x * 256 + threadIdx.x;  // B*C*CI/4 threads
    int j4 = (idx & 31) * 4;
    int r  = (idx >> 5) & (C - 1);
    int b  = idx >> 13;
    const float* Sb = S + (size_t)b * CI * CI;
    const float* wr = w_w + (size_t)r * CI;
    float4 a = {0.f, 0.f, 0.f, 0.f};
    for (int k = 0; k < CI; ++k) {
        float wv = wr[k];
        float4 s = *reinterpret_cast<const float4*>(&Sb[(size_t)k * CI + j4]);
        a.x += wv * s.x; a.y += wv * s.y; a.z += wv * s.z; a.w += wv * s.w;
    }
    const float sc = 1.f / NN;
    a.x *= sc; a.y *= sc; a.z *= sc; a.w *= sc;
    *reinterpret_cast<float4*>(&M[((size_t)b * C + r) * CI + j4]) = a;
}

// K3b: W2[b] = M[b] @ theta_w -> TILED bf16 hi/lo; b2[b] = M[b]@theta_b + w_b
__global__ __launch_bounds__(256) void k3b_W2(
    const float* __restrict__ M, const float* __restrict__ theta_w,
    const float* __restrict__ theta_b, const float* __restrict__ w_b,
    unsigned short* __restrict__ w2h, unsigned short* __restrict__ w2l,
    float* __restrict__ b2)
{
    int idx = blockIdx.x * 256 + threadIdx.x;  // B*C*C/8 = 32768 threads
    int c8 = idx & 31;
    int r  = (idx >> 5) & (C - 1);
    int b  = idx >> 13;
    const float* Mb = M + ((size_t)b * C + r) * CI;
    float4 a0 = {0.f, 0.f, 0.f, 0.f}, a1 = {0.f, 0.f, 0.f, 0.f};
    for (int k = 0; k < CI; ++k) {
        float mv = Mb[k];
        const float* tw = &theta_w[(size_t)k * C + c8 * 8];
        float4 t0 = *reinterpret_cast<const float4*>(tw);
        float4 t1 = *reinterpret_cast<const float4*>(tw + 4);
        a0.x += mv * t0.x; a0.y += mv * t0.y; a0.z += mv * t0.z; a0.w += mv * t0.w;
        a1.x += mv * t1.x; a1.y += mv * t1.y; a1.z += mv * t1.z; a1.w += mv * t1.w;
    }
    float av[8] = {a0.x, a0.y, a0.z, a0.w, a1.x, a1.y, a1.z, a1.w};
    s16x8 hs, ls;
    #pragma unroll
    for (int i = 0; i < 8; ++i) {
        unsigned short h = f2bf(av[i]);
        hs[i] = (short)h; ls[i] = (short)f2bf(av[i] - bf2f(h));
    }
    size_t dst = ((size_t)b * 2 + (r >> 7)) * 32768 + (size_t)c8 * 1024 + (r & 127) * 8;
    *reinterpret_cast<s16x8*>(w2h + dst) = hs;
    *reinterpret_cast<s16x8*>(w2l + dst) = ls;
    if (c8 == 0) {
        float bv = 0.f;
        for (int k = 0; k < CI; ++k) bv += Mb[k] * theta_b[k];
        b2[(size_t)b * C + r] = bv + w_b[r];
    }
}

// K4b: finalize BN scale/shift
__global__ void k4b_stats(const float* __restrict__ gsum, const float* __restrict__ gsq,
                          const float* __restrict__ gamma, const float* __restrict__ beta,
                          float* __restrict__ a, float* __restrict__ sh)
{
    int c = threadIdx.x;
    const float invBT = 1.f / (float)(B * T);
    float mean = gsum[c] * invBT;
    float var  = gsq[c] * invBT - mean * mean;
    float av = gamma[c] * rsqrtf(var + 1e-5f);
    a[c]  = av;
    sh[c] = beta[c] - av * mean;
}

extern "C" void kernel_launch(void* const* d_in, const int* in_sizes, int n_in,
                              void* d_out, int out_size, void* d_ws, size_t ws_size,
                              hipStream_t stream)
{
    const float* x       = (const float*)d_in[0];
    const float* theta_w = (const float*)d_in[1];
    const float* theta_b = (const float*)d_in[2];
    const float* phi_w   = (const float*)d_in[3];
    const float* phi_b   = (const float*)d_in[4];
    const float* g_w     = (const float*)d_in[5];
    const float* g_b     = (const float*)d_in[6];
    const float* w_w     = (const float*)d_in[7];
    const float* w_b     = (const float*)d_in[8];
    const float* gamma   = (const float*)d_in[9];
    const float* beta    = (const float*)d_in[10];
    float* out = (float*)d_out;
    char* ws = (char*)d_ws;

    unsigned short* xth = (unsigned short*)(ws + O_XTH);
    unsigned short* xtl = (unsigned short*)(ws + O_XTL);
    unsigned short* wsh = (unsigned short*)(ws + O_WSH);
    unsigned short* wsl = (unsigned short*)(ws + O_WSL);
    unsigned short* ph  = (unsigned short*)(ws + O_PH);
    unsigned short* pl  = (unsigned short*)(ws + O_PL);
    unsigned short* gh  = (unsigned short*)(ws + O_GH);
    unsigned short* gl  = (unsigned short*)(ws + O_GL);
    float* Sbuf  = (float*)(ws + O_S);
    float* Mbuf  = (float*)(ws + O_M);
    unsigned short* w2h = (unsigned short*)(ws + O_W2H);
    unsigned short* w2l = (unsigned short*)(ws + O_W2L);
    float* b2    = (float*)(ws + O_B2);
    float* gsum  = (float*)(ws + O_GS);
    float* gsq   = (float*)(ws + O_GQ);
    float* abuf  = (float*)(ws + O_A);
    float* shbuf = (float*)(ws + O_SH);

    hipMemsetAsync(Sbuf, 0, (size_t)B * CI * CI * sizeof(float), stream);
    hipMemsetAsync(gsum, 0, 2 * (size_t)C * sizeof(float), stream);

    k0_split<<<dim3(T / 64, C / 64, B), 256, 0, stream>>>(x, xth, xtl);
    k0w<<<dim3(32), 256, 0, stream>>>(phi_w, g_w, wsh, wsl);
    k1_mfma<<<dim3(T / 128, 2, B), 256, 0, stream>>>(xth, xtl, wsh, wsl, phi_b, g_b,
                                                     ph, pl, gh, gl);
    k2_mfma<<<dim3(NN / 128, B), 256, 0, stream>>>(ph, pl, gh, gl, Sbuf);
    k3a_M<<<dim3(B * C * CI / 4 / 256), 256, 0, stream>>>(w_w, Sbuf, Mbuf);
    k3b_W2<<<dim3(B * C * C / 8 / 256), 256, 0, stream>>>(Mbuf, theta_w, theta_b, w_b,
                                                          w2h, w2l, b2);
    k45_mfma<0><<<dim3(T / 128, C / 128, B), 256, 0, stream>>>(
        xth, xtl, w2h, w2l, b2, x, abuf, shbuf, gsum, gsq, out);
    k4b_stats<<<1, C, 0, stream>>>(gsum, gsq, gamma, beta, abuf, shbuf);
    k45_mfma<1><<<dim3(T / 128, C / 128, B), 256, 0, stream>>>(
        xth, xtl, w2h, w2l, b2, x, abuf, shbuf, gsum, gsq, out);
}

// Round 11
// 243.625 us; speedup vs baseline: 1.0402x; 1.0402x over previous
//
#include <hip/hip_runtime.h>
#include <hip/hip_bf16.h>

// NonLocalBlock1D, algebraically collapsed + split-bf16 MFMA.
//   S[b]  = g_pool[b] @ phi_pool[b]^T      (128x128)
//   M[b]  = w_w @ S[b] / N                 (256x128)
//   W2[b] = M[b] @ theta_w                 (256x256), b2[b] = M[b]@theta_b + w_b
//   wy[b] = W2[b] @ x[b] + b2[b]           (GEMM once: stats + bf16 wy store)
//   out   = BN(wy) + x                     (memory-bound elementwise pass)
// Round-10/11: cooperative grid.sync fusion REVERTED (silent launch failure at
// exact 2-blocks/CU occupancy -> out never written). Instead: single GEMM
// pass stores wy bf16 (16MB, overlaps dead pool buffers), then a ~15us
// elementwise BN-apply. __launch_bounds__(256,2) kept on GEMM kernels to
// test the R8 ILP hypothesis (R5: VGPR=64 starved ILP, MfmaUtil 10%).

constexpr int B = 4, C = 256, CI = 128, T = 8192, NN = 4096;

using s16x8 = __attribute__((ext_vector_type(8))) short;
using f32x4 = __attribute__((ext_vector_type(4))) float;

__device__ __forceinline__ unsigned short f2bf(float f) {
    unsigned int x = __float_as_uint(f);
    unsigned int r = (x + 0x7fffu + ((x >> 16) & 1u)) >> 16;   // RNE
    return (unsigned short)r;
}
__device__ __forceinline__ float bf2f(unsigned short u) {
    return __uint_as_float((unsigned int)u << 16);
}

#define MFMA(a, b, c) __builtin_amdgcn_mfma_f32_16x16x32_bf16((a), (b), (c), 0, 0, 0)

__device__ __forceinline__ void glds16(const unsigned short* g, void* l) {
    __builtin_amdgcn_global_load_lds(
        (const __attribute__((address_space(1))) unsigned int*)(g),
        (__attribute__((address_space(3))) unsigned int*)(l), 16, 0, 0);
}

// Tiled layout: tile = 128 rows x 256 k of bf16 = 65536 B = 32768 u16.
//   u16 offset(tile, kc, row, j) = tile*32768 + kc*1024 + row*8 + j
// xth/xtl: tile = b*(T/128) + t/128, row = t%128, kc = c/8.
// wsh/wsl: tile = isG (phi=0, g=1), row = o%128.
// w2h/w2l: tile = b*2 + o/128.

// ---- ws layout (bytes) ----
constexpr size_t SZ_XT = (size_t)B * T * C * 2;        // 16MB each
constexpr size_t O_XTH = 0;
constexpr size_t O_XTL = O_XTH + SZ_XT;
constexpr size_t O_WSH = O_XTL + SZ_XT;                // stacked [phi;g] weights bf16
constexpr size_t O_WSL = O_WSH + (size_t)C * C * 2;
constexpr size_t SZ_P  = (size_t)B * CI * NN * 2;      // 4MB each pool array
constexpr size_t O_PH  = O_WSL + (size_t)C * C * 2;
constexpr size_t O_PL  = O_PH + SZ_P;
constexpr size_t O_GH  = O_PL + SZ_P;
constexpr size_t O_GL  = O_GH + SZ_P;
constexpr size_t O_WY  = O_PH;                         // bf16 wy (B,C,T) = 16MB,
                                                       // overlays pools (dead after k2)
constexpr size_t O_S   = O_GL + SZ_P;                  // fp32 B*CI*CI
constexpr size_t O_M   = O_S  + (size_t)B * CI * CI * 4;
constexpr size_t O_W2H = O_M  + (size_t)B * C * CI * 4;
constexpr size_t O_W2L = O_W2H + (size_t)B * C * C * 2;
constexpr size_t O_B2  = O_W2L + (size_t)B * C * C * 2;
constexpr size_t O_GS  = O_B2 + (size_t)B * C * 4;
constexpr size_t O_GQ  = O_GS + (size_t)C * 4;
constexpr size_t O_A   = O_GQ + (size_t)C * 4;
constexpr size_t O_SH  = O_A  + (size_t)C * 4;

// K0: x (B,C,T) fp32 -> tiled hi/lo bf16
__global__ __launch_bounds__(256) void k0_split(
    const float* __restrict__ x, unsigned short* __restrict__ xth,
    unsigned short* __restrict__ xtl)
{
    __shared__ float xs[64][65];   // [t][c], padded
    int t0 = blockIdx.x * 64, c0 = blockIdx.y * 64, b = blockIdx.z;
    int tid = threadIdx.x;
    const float* xb = x + (size_t)b * C * T;
    #pragma unroll
    for (int p = 0; p < 4; ++p) {
        int idx = tid + p * 256;
        int cr = idx >> 4;           // c-local
        int tg = (idx & 15) * 4;     // t-local
        float4 v = *reinterpret_cast<const float4*>(xb + (size_t)(c0 + cr) * T + t0 + tg);
        xs[tg + 0][cr] = v.x; xs[tg + 1][cr] = v.y;
        xs[tg + 2][cr] = v.z; xs[tg + 3][cr] = v.w;
    }
    __syncthreads();
    size_t tileBase = ((size_t)b * (T / 128) + (t0 >> 7)) * 32768;
    int trBase = t0 & 127;           // 0 or 64
    #pragma unroll
    for (int p = 0; p < 2; ++p) {
        int idx = tid + p * 256;
        int kcL = idx >> 6;          // 0..7 (chunk within this 64-c block)
        int tl  = idx & 63;
        s16x8 hs, ls;
        #pragma unroll
        for (int j = 0; j < 8; ++j) {
            float v = xs[tl][kcL * 8 + j];
            unsigned short h = f2bf(v);
            unsigned short l = f2bf(v - bf2f(h));
            hs[j] = (short)h; ls[j] = (short)l;
        }
        size_t dst = tileBase + (size_t)((c0 >> 3) + kcL) * 1024 + (trBase + tl) * 8;
        *reinterpret_cast<s16x8*>(xth + dst) = hs;
        *reinterpret_cast<s16x8*>(xtl + dst) = ls;
    }
}

// K0w: stack [phi_w; g_w] -> tiled hi/lo bf16 (tile0=phi, tile1=g)
__global__ __launch_bounds__(256) void k0w(
    const float* __restrict__ phi_w, const float* __restrict__ g_w,
    unsigned short* __restrict__ wsh, unsigned short* __restrict__ wsl)
{
    int idx = blockIdx.x * 256 + threadIdx.x;   // 8192 threads
    int c8 = idx & 31, row = idx >> 5;          // row 0..255
    const float* src = (row < CI) ? &phi_w[(size_t)row * C + c8 * 8]
                                  : &g_w[(size_t)(row - CI) * C + c8 * 8];
    s16x8 hs, ls;
    #pragma unroll
    for (int j = 0; j < 8; ++j) {
        float v = src[j];
        unsigned short h = f2bf(v);
        hs[j] = (short)h; ls[j] = (short)f2bf(v - bf2f(h));
    }
    size_t dst = (size_t)(row >> 7) * 32768 + (size_t)c8 * 1024 + (row & 127) * 8;
    *reinterpret_cast<s16x8*>(wsh + dst) = hs;
    *reinterpret_cast<s16x8*>(wsl + dst) = ls;
}

// ---- shared GEMM core ----
// Block: 128 t x 128 o, 4 waves (2 wt x 2 wo). A staged in LDS (64KB,
// [kc][row]); B direct from tiled global. 3 phases: (xh,Bh)x8, (xh,Bl)x8,
// then restage A=xl, (xl,Bh)x8.
#define STAGE_A(srcT) {                                                        \
    _Pragma("unroll")                                                          \
    for (int i_ = 0; i_ < 16; ++i_)                                            \
        glds16((srcT) + (size_t)(w * 8192 + i_ * 512 + lane * 8),              \
               arena + w * 16384 + i_ * 1024);                                 \
}

#define K8(BT) {                                                               \
    _Pragma("unroll")                                                          \
    for (int ks_ = 0; ks_ < 8; ++ks_) {                                        \
        s16x8 af[4], bfr[4];                                                   \
        _Pragma("unroll")                                                      \
        for (int ts_ = 0; ts_ < 4; ++ts_)                                      \
            af[ts_] = *(const s16x8*)(arena + (ks_ * 4 + lk) * 2048            \
                                      + (wt * 64 + ts_ * 16 + lr) * 16);       \
        _Pragma("unroll")                                                      \
        for (int os_ = 0; os_ < 4; ++os_)                                      \
            bfr[os_] = *(const s16x8*)((BT) + (size_t)(ks_ * 4 + lk) * 1024    \
                                       + (wo * 64 + os_ * 16 + lr) * 8);       \
        _Pragma("unroll")                                                      \
        for (int os_ = 0; os_ < 4; ++os_)                                      \
            _Pragma("unroll")                                                  \
            for (int ts_ = 0; ts_ < 4; ++ts_)                                  \
                acc[os_][ts_] = MFMA(af[ts_], bfr[os_], acc[os_][ts_]);        \
    }                                                                          \
}

#define GEMM_3PHASE(aT_h, aT_l, bT_h, bT_l) {                                  \
    STAGE_A(aT_h);                                                             \
    __syncthreads();                                                           \
    K8(bT_h);                                                                  \
    K8(bT_l);                                                                  \
    __syncthreads();                                                           \
    STAGE_A(aT_l);                                                             \
    __syncthreads();                                                           \
    K8(bT_h);                                                                  \
}

// K1: pooled [phi;g] conv. Grid (T/128, 2, B): y=0 -> phi, y=1 -> g.
__global__ __launch_bounds__(256, 2) void k1_mfma(
    const unsigned short* __restrict__ xth, const unsigned short* __restrict__ xtl,
    const unsigned short* __restrict__ wsh, const unsigned short* __restrict__ wsl,
    const float* __restrict__ phi_b, const float* __restrict__ g_b,
    unsigned short* __restrict__ ph, unsigned short* __restrict__ pl,
    unsigned short* __restrict__ gh, unsigned short* __restrict__ gl)
{
    const int b = blockIdx.z, t0 = blockIdx.x * 128, isG = blockIdx.y;
    __shared__ __align__(16) char arena[65536];
    const int tid = threadIdx.x, lane = tid & 63, w = tid >> 6;
    const int lr = lane & 15, lk = lane >> 4;
    const int wt = w >> 1, wo = w & 1;

    const unsigned short* aTh = xth + ((size_t)b * (T / 128) + (t0 >> 7)) * 32768;
    const unsigned short* aTl = xtl + ((size_t)b * (T / 128) + (t0 >> 7)) * 32768;
    const unsigned short* bTh = wsh + (size_t)isG * 32768;
    const unsigned short* bTl = wsl + (size_t)isG * 32768;

    f32x4 acc[4][4];
    #pragma unroll
    for (int i = 0; i < 4; ++i)
        #pragma unroll
        for (int j = 0; j < 4; ++j) acc[i][j] = (f32x4){0.f, 0.f, 0.f, 0.f};

    GEMM_3PHASE(aTh, aTl, bTh, bTl)
    __syncthreads();   // arena free for pool overlay

    unsigned int (*pool_s)[65] = (unsigned int (*)[65])arena;
    const float* biasArr = isG ? g_b : phi_b;
    #pragma unroll
    for (int os = 0; os < 4; ++os) {
        int oL = wo * 64 + os * 16 + lr;
        float bias = biasArr[oL];
        #pragma unroll
        for (int ts = 0; ts < 4; ++ts) {
            f32x4 v = acc[os][ts];
            float m0 = fmaxf(v[0], v[1]) + bias;
            float m1 = fmaxf(v[2], v[3]) + bias;
            int nl = wt * 32 + ts * 8 + lk * 2;   // t = wt*64+ts*16+lk*4+r -> n=t/2
            unsigned short h0 = f2bf(m0), h1 = f2bf(m1);
            pool_s[oL][nl]     = (unsigned int)h0 | ((unsigned int)f2bf(m0 - bf2f(h0)) << 16);
            pool_s[oL][nl + 1] = (unsigned int)h1 | ((unsigned int)f2bf(m1 - bf2f(h1)) << 16);
        }
    }
    __syncthreads();
    int oL = tid >> 1, seg = tid & 1;
    size_t n0 = (size_t)(t0 >> 1) + seg * 32;
    unsigned short* dh = (isG ? gh : ph) + ((size_t)b * CI + oL) * NN + n0;
    unsigned short* dl = (isG ? gl : pl) + ((size_t)b * CI + oL) * NN + n0;
    #pragma unroll
    for (int g4 = 0; g4 < 4; ++g4) {
        s16x8 hs, ls;
        #pragma unroll
        for (int j = 0; j < 8; ++j) {
            unsigned int u = pool_s[oL][seg * 32 + g4 * 8 + j];
            hs[j] = (short)(u & 0xffffu);
            ls[j] = (short)(u >> 16);
        }
        *reinterpret_cast<s16x8*>(dh + g4 * 8) = hs;
        *reinterpret_cast<s16x8*>(dl + g4 * 8) = ls;
    }
}

// K45: wy = W2[b]@x + b2 computed ONCE. Stats atomics + bf16 wy store.
__global__ __launch_bounds__(256, 2) void k45_stats(
    const unsigned short* __restrict__ xth, const unsigned short* __restrict__ xtl,
    const unsigned short* __restrict__ w2h, const unsigned short* __restrict__ w2l,
    const float* __restrict__ b2, unsigned short* __restrict__ wy,
    float* __restrict__ gsum, float* __restrict__ gsq)
{
    const int b = blockIdx.z, t0 = blockIdx.x * 128, oHalf = blockIdx.y;
    const int o0 = oHalf * 128;
    __shared__ __align__(16) char arena[65536];
    const int tid = threadIdx.x, lane = tid & 63, w = tid >> 6;
    const int lr = lane & 15, lk = lane >> 4;
    const int wt = w >> 1, wo = w & 1;

    const unsigned short* aTh = xth + ((size_t)b * (T / 128) + (t0 >> 7)) * 32768;
    const unsigned short* aTl = xtl + ((size_t)b * (T / 128) + (t0 >> 7)) * 32768;
    const unsigned short* bTh = w2h + ((size_t)b * 2 + oHalf) * 32768;
    const unsigned short* bTl = w2l + ((size_t)b * 2 + oHalf) * 32768;

    f32x4 acc[4][4];
    #pragma unroll
    for (int i = 0; i < 4; ++i)
        #pragma unroll
        for (int j = 0; j < 4; ++j) acc[i][j] = (f32x4){0.f, 0.f, 0.f, 0.f};

    GEMM_3PHASE(aTh, aTl, bTh, bTl)

    #pragma unroll
    for (int os = 0; os < 4; ++os) {
        int o = o0 + wo * 64 + os * 16 + lr;
        float bv = b2[(size_t)b * C + o];
        float s = 0.f, q = 0.f;
        #pragma unroll
        for (int ts = 0; ts < 4; ++ts) {
            int t = t0 + wt * 64 + ts * 16 + lk * 4;
            ushort4 pk;
            float v0 = acc[os][ts][0] + bv;
            float v1 = acc[os][ts][1] + bv;
            float v2 = acc[os][ts][2] + bv;
            float v3 = acc[os][ts][3] + bv;
            s += v0 + v1 + v2 + v3;
            q += v0 * v0 + v1 * v1 + v2 * v2 + v3 * v3;
            pk.x = f2bf(v0); pk.y = f2bf(v1); pk.z = f2bf(v2); pk.w = f2bf(v3);
            *reinterpret_cast<ushort4*>(&wy[((size_t)b * C + o) * T + t]) = pk;
        }
        s += __shfl_xor(s, 16); s += __shfl_xor(s, 32);
        q += __shfl_xor(q, 16); q += __shfl_xor(q, 32);
        if (lk == 0) { atomicAdd(&gsum[o], s); atomicAdd(&gsq[o], q); }
    }
}

// K4b: finalize BN scale/shift
__global__ void k4b_stats(const float* __restrict__ gsum, const float* __restrict__ gsq,
                          const float* __restrict__ gamma, const float* __restrict__ beta,
                          float* __restrict__ a, float* __restrict__ sh)
{
    int c = threadIdx.x;
    const float invBT = 1.f / (float)(B * T);
    float mean = gsum[c] * invBT;
    float var  = gsq[c] * invBT - mean * mean;
    float av = gamma[c] * rsqrtf(var + 1e-5f);
    a[c]  = av;
    sh[c] = beta[c] - av * mean;
}

// K5: out = a[c]*wy + sh[c] + x   (memory-bound elementwise)
__global__ __launch_bounds__(256) void k5_apply(
    const float* __restrict__ x, const unsigned short* __restrict__ wy,
    const float* __restrict__ a, const float* __restrict__ sh,
    float* __restrict__ out)
{
    size_t total4 = (size_t)B * C * T / 4;
    for (size_t i = (size_t)blockIdx.x * blockDim.x + threadIdx.x; i < total4;
         i += (size_t)gridDim.x * blockDim.x) {
        size_t e = i * 4;
        int c = (int)((e / T) % C);
        ushort4 w4 = *reinterpret_cast<const ushort4*>(&wy[e]);
        float4 x4 = reinterpret_cast<const float4*>(x)[i];
        float av = a[c], sv = sh[c];
        float4 o;
        o.x = av * bf2f(w4.x) + sv + x4.x;
        o.y = av * bf2f(w4.y) + sv + x4.y;
        o.z = av * bf2f(w4.z) + sv + x4.z;
        o.w = av * bf2f(w4.w) + sv + x4.w;
        reinterpret_cast<float4*>(out)[i] = o;
    }
}

// K2: S[b,i,j] = sum_n g[i,n]*phi[j,n], split MFMA, atomic partials.
__global__ __launch_bounds__(256, 2) void k2_mfma(
    const unsigned short* __restrict__ ph, const unsigned short* __restrict__ pl,
    const unsigned short* __restrict__ gh, const unsigned short* __restrict__ gl,
    float* __restrict__ S)
{
    int b = blockIdx.y, n0 = blockIdx.x * 128;
    int tid = threadIdx.x, lane = tid & 63, w = tid >> 6;
    int lr = lane & 15, lk = lane >> 4;

    f32x4 acc[2][8];   // [isub][jsub]
    #pragma unroll
    for (int i = 0; i < 2; ++i)
        #pragma unroll
        for (int j = 0; j < 8; ++j) acc[i][j] = (f32x4){0.f, 0.f, 0.f, 0.f};

    const unsigned short* ah_b = gh + ((size_t)b * CI + w * 32 + lr) * NN + n0 + lk * 8;
    const unsigned short* al_b = gl + ((size_t)b * CI + w * 32 + lr) * NN + n0 + lk * 8;
    const unsigned short* bh_b = ph + ((size_t)b * CI + lr) * NN + n0 + lk * 8;
    const unsigned short* bl_b = pl + ((size_t)b * CI + lr) * NN + n0 + lk * 8;

    for (int ks = 0; ks < 4; ++ks) {
        s16x8 Ah[2], Al[2], Bh[8], Bl[8];
        #pragma unroll
        for (int is = 0; is < 2; ++is) {
            Ah[is] = *reinterpret_cast<const s16x8*>(ah_b + (size_t)is * 16 * NN + ks * 32);
            Al[is] = *reinterpret_cast<const s16x8*>(al_b + (size_t)is * 16 * NN + ks * 32);
        }
        #pragma unroll
        for (int js = 0; js < 8; ++js) {
            Bh[js] = *reinterpret_cast<const s16x8*>(bh_b + (size_t)js * 16 * NN + ks * 32);
            Bl[js] = *reinterpret_cast<const s16x8*>(bl_b + (size_t)js * 16 * NN + ks * 32);
        }
        #pragma unroll
        for (int is = 0; is < 2; ++is)
            #pragma unroll
            for (int js = 0; js < 8; ++js) {
                acc[is][js] = MFMA(Ah[is], Bh[js], acc[is][js]);
                acc[is][js] = MFMA(Al[is], Bh[js], acc[is][js]);
                acc[is][js] = MFMA(Ah[is], Bl[js], acc[is][js]);
            }
    }
    #pragma unroll
    for (int is = 0; is < 2; ++is) {
        int i0 = w * 32 + is * 16 + lk * 4;
        #pragma unroll
        for (int js = 0; js < 8; ++js) {
            int j = js * 16 + lr;
            #pragma unroll
            for (int r = 0; r < 4; ++r)
                atomicAdd(&S[((size_t)b * CI + i0 + r) * CI + j], acc[is][js][r]);
        }
    }
}

// K3a: M[b] = w_w @ S[b] / N   (float4 over j)
__global__ __launch_bounds__(256) void k3a_M(
    const float* __restrict__ w_w, const float* __restrict__ S, float* __restrict__ M)
{
    int idx = blockIdx.x * 256 + threadIdx.x;  // B*C*CI/4 threads
    int j4 = (idx & 31) * 4;
    int r  = (idx >> 5) & (C - 1);
    int b  = idx >> 13;
    const float* Sb = S + (size_t)b * CI * CI;
    const float* wr = w_w + (size_t)r * CI;
    float4 a = {0.f, 0.f, 0.f, 0.f};
    for (int k = 0; k < CI; ++k) {
        float wv = wr[k];
        float4 s = *reinterpret_cast<const float4*>(&Sb[(size_t)k * CI + j4]);
        a.x += wv * s.x; a.y += wv * s.y; a.z += wv * s.z; a.w += wv * s.w;
    }
    const float sc = 1.f / NN;
    a.x *= sc; a.y *= sc; a.z *= sc; a.w *= sc;
    *reinterpret_cast<float4*>(&M[((size_t)b * C + r) * CI + j4]) = a;
}

// K3b: W2[b] = M[b] @ theta_w -> TILED bf16 hi/lo; b2[b] = M[b]@theta_b + w_b
__global__ __launch_bounds__(256) void k3b_W2(
    const float* __restrict__ M, const float* __restrict__ theta_w,
    const float* __restrict__ theta_b, const float* __restrict__ w_b,
    unsigned short* __restrict__ w2h, unsigned short* __restrict__ w2l,
    float* __restrict__ b2)
{
    int idx = blockIdx.x * 256 + threadIdx.x;  // B*C*C/8 = 32768 threads
    int c8 = idx & 31;
    int r  = (idx >> 5) & (C - 1);
    int b  = idx >> 13;
    const float* Mb = M + ((size_t)b * C + r) * CI;
    float4 a0 = {0.f, 0.f, 0.f, 0.f}, a1 = {0.f, 0.f, 0.f, 0.f};
    for (int k = 0; k < CI; ++k) {
        float mv = Mb[k];
        const float* tw = &theta_w[(size_t)k * C + c8 * 8];
        float4 t0 = *reinterpret_cast<const float4*>(tw);
        float4 t1 = *reinterpret_cast<const float4*>(tw + 4);
        a0.x += mv * t0.x; a0.y += mv * t0.y; a0.z += mv * t0.z; a0.w += mv * t0.w;
        a1.x += mv * t1.x; a1.y += mv * t1.y; a1.z += mv * t1.z; a1.w += mv * t1.w;
    }
    float av[8] = {a0.x, a0.y, a0.z, a0.w, a1.x, a1.y, a1.z, a1.w};
    s16x8 hs, ls;
    #pragma unroll
    for (int i = 0; i < 8; ++i) {
        unsigned short h = f2bf(av[i]);
        hs[i] = (short)h; ls[i] = (short)f2bf(av[i] - bf2f(h));
    }
    size_t dst = ((size_t)b * 2 + (r >> 7)) * 32768 + (size_t)c8 * 1024 + (r & 127) * 8;
    *reinterpret_cast<s16x8*>(w2h + dst) = hs;
    *reinterpret_cast<s16x8*>(w2l + dst) = ls;
    if (c8 == 0) {
        float bv = 0.f;
        for (int k = 0; k < CI; ++k) bv += Mb[k] * theta_b[k];
        b2[(size_t)b * C + r] = bv + w_b[r];
    }
}

extern "C" void kernel_launch(void* const* d_in, const int* in_sizes, int n_in,
                              void* d_out, int out_size, void* d_ws, size_t ws_size,
                              hipStream_t stream)
{
    const float* x       = (const float*)d_in[0];
    const float* theta_w = (const float*)d_in[1];
    const float* theta_b = (const float*)d_in[2];
    const float* phi_w   = (const float*)d_in[3];
    const float* phi_b   = (const float*)d_in[4];
    const float* g_w     = (const float*)d_in[5];
    const float* g_b     = (const float*)d_in[6];
    const float* w_w     = (const float*)d_in[7];
    const float* w_b     = (const float*)d_in[8];
    const float* gamma   = (const float*)d_in[9];
    const float* beta    = (const float*)d_in[10];
    float* out = (float*)d_out;
    char* ws = (char*)d_ws;

    unsigned short* xth = (unsigned short*)(ws + O_XTH);
    unsigned short* xtl = (unsigned short*)(ws + O_XTL);
    unsigned short* wsh = (unsigned short*)(ws + O_WSH);
    unsigned short* wsl = (unsigned short*)(ws + O_WSL);
    unsigned short* ph  = (unsigned short*)(ws + O_PH);
    unsigned short* pl  = (unsigned short*)(ws + O_PL);
    unsigned short* gh  = (unsigned short*)(ws + O_GH);
    unsigned short* gl  = (unsigned short*)(ws + O_GL);
    unsigned short* wy  = (unsigned short*)(ws + O_WY);   // overlays pools
    float* Sbuf  = (float*)(ws + O_S);
    float* Mbuf  = (float*)(ws + O_M);
    unsigned short* w2h = (unsigned short*)(ws + O_W2H);
    unsigned short* w2l = (unsigned short*)(ws + O_W2L);
    float* b2    = (float*)(ws + O_B2);
    float* gsum  = (float*)(ws + O_GS);
    float* gsq   = (float*)(ws + O_GQ);
    float* abuf  = (float*)(ws + O_A);
    float* shbuf = (float*)(ws + O_SH);

    hipMemsetAsync(Sbuf, 0, (size_t)B * CI * CI * sizeof(float), stream);
    hipMemsetAsync(gsum, 0, 2 * (size_t)C * sizeof(float), stream);

    k0_split<<<dim3(T / 64, C / 64, B), 256, 0, stream>>>(x, xth, xtl);
    k0w<<<dim3(32), 256, 0, stream>>>(phi_w, g_w, wsh, wsl);
    k1_mfma<<<dim3(T / 128, 2, B), 256, 0, stream>>>(xth, xtl, wsh, wsl, phi_b, g_b,
                                                     ph, pl, gh, gl);
    k2_mfma<<<dim3(NN / 128, B), 256, 0, stream>>>(ph, pl, gh, gl, Sbuf);
    k3a_M<<<dim3(B * C * CI / 4 / 256), 256, 0, stream>>>(w_w, Sbuf, Mbuf);
    k3b_W2<<<dim3(B * C * C / 8 / 256), 256, 0, stream>>>(Mbuf, theta_w, theta_b, w_b,
                                                          w2h, w2l, b2);
    k45_stats<<<dim3(T / 128, C / 128, B), 256, 0, stream>>>(
        xth, xtl, w2h, w2l, b2, wy, gsum, gsq);
    k4b_stats<<<1, C, 0, stream>>>(gsum, gsq, gamma, beta, abuf, shbuf);
    k5_apply<<<2048, 256, 0, stream>>>(x, wy, abuf, shbuf, out);
}